// Round 15
// baseline (644.147 us; speedup 1.0000x reference)
//
#include <hip/hip_runtime.h>
#include <hip/hip_bf16.h>

// GPT-2-ish forward: L=4, B=2, T=1024, C=1024, H=16, D=64, V=50257.
// Round 15: GEMM tile 128x128 -> 64x128 (A 64 rows, B 128 rows). Grids become
// exact multiples of 256 CUs (qkv 768=3.0 waves, fc/proj/fcproj 1024=4.0,
// KV 512=2.0) and 4 blocks/CU resident (m114 overlap regime). Same MFMA
// order/swizzle -> bit-identical numerics. Rest frozen from round 14.

#define TT 1024
#define CC 1024
#define NHEAD 16
#define DHEAD 64
#define NBATCH 2
#define VOCAB 50257

typedef __attribute__((ext_vector_type(8))) short bf16x8;
typedef __attribute__((ext_vector_type(4))) float f32x4;
typedef __attribute__((ext_vector_type(16))) float f32x16;

#define GPTR(p) (const __attribute__((address_space(1))) void*)(p)
#define LPTR(p) (__attribute__((address_space(3))) void*)(p)

__device__ __forceinline__ unsigned short f2bf(float f) {
  union { float f; unsigned u; } v; v.f = f;
  unsigned r = v.u + 0x7fffu + ((v.u >> 16) & 1u);   // RNE
  return (unsigned short)(r >> 16);
}
__device__ __forceinline__ float bf2f(unsigned short u) {
  union { unsigned u; float f; } v; v.u = ((unsigned)u) << 16;
  return v.f;
}

__device__ __forceinline__ f32x4 mfma_bf16(bf16x8 a, bf16x8 b, f32x4 c) {
  return __builtin_amdgcn_mfma_f32_16x16x32_bf16(a, b, c, 0, 0, 0);
}
__device__ __forceinline__ f32x16 mfma32_bf16(bf16x8 a, bf16x8 b, f32x16 c) {
  return __builtin_amdgcn_mfma_f32_32x32x16_bf16(a, b, c, 0, 0, 0);
}

__device__ __forceinline__ unsigned pk2(float lo, float hi) {
  return (unsigned)f2bf(lo) | ((unsigned)f2bf(hi) << 16);
}

// ---------------- prep: embedding+LN (blocks 0..2047) + weight convert ----------------
__global__ __launch_bounds__(256) void prep_k(const int* __restrict__ idx,
    const float* __restrict__ wte, const float* __restrict__ wpe,
    const float* __restrict__ lw, const float* __restrict__ lb,
    float* __restrict__ x, unsigned short* __restrict__ h,
    const float* __restrict__ attn_w, unsigned short* __restrict__ wt_attn,
    const float* __restrict__ proj_w, unsigned short* __restrict__ wt_proj,
    const float* __restrict__ fc_w,   unsigned short* __restrict__ wt_fc,
    const float* __restrict__ fcp_w,  unsigned short* __restrict__ wt_fcp)
{
  __shared__ float tile[64][65];
  const int tid = threadIdx.x;
  if (blockIdx.x < 2048) {
    const int row = blockIdx.x;
    const int t = row & (TT - 1);
    const int tok = idx[row];
    const int wave = tid >> 6, lane = tid & 63;
    float4 va = ((const float4*)(wte + (size_t)tok * CC))[tid];
    float4 vp = ((const float4*)(wpe + (size_t)t * CC))[tid];
    float4 v = make_float4(va.x + vp.x, va.y + vp.y, va.z + vp.z, va.w + vp.w);
    ((float4*)(x + (size_t)row * CC))[tid] = v;
    float s  = v.x + v.y + v.z + v.w;
    float ss = v.x*v.x + v.y*v.y + v.z*v.z + v.w*v.w;
#pragma unroll
    for (int off = 1; off < 64; off <<= 1) {
      s  += __shfl_xor(s, off, 64);
      ss += __shfl_xor(ss, off, 64);
    }
    if (lane == 0) { tile[0][wave] = s; tile[0][4 + wave] = ss; }
    __syncthreads();
    s  = tile[0][0] + tile[0][1] + tile[0][2] + tile[0][3];
    ss = tile[0][4] + tile[0][5] + tile[0][6] + tile[0][7];
    float mu = s * (1.f / CC);
    float var = ss * (1.f / CC) - mu * mu;
    float rstd = rsqrtf(var + 1e-5f);
    float4 wv = ((const float4*)lw)[tid];
    float4 bv = ((const float4*)lb)[tid];
    float o0 = (v.x - mu) * rstd * wv.x + bv.x;
    float o1 = (v.y - mu) * rstd * wv.y + bv.y;
    float o2 = (v.z - mu) * rstd * wv.z + bv.z;
    float o3 = (v.w - mu) * rstd * wv.w + bv.w;
    ((uint2*)(h + (size_t)row * CC))[tid] = make_uint2(pk2(o0, o1), pk2(o2, o3));
    return;
  }
  int b = blockIdx.x - 2048;
  const float* W; unsigned short* Wt; int K, N, kx, ny;
  if (b < 3072) {                 // attn: 4 layers x (16 x 48)
    int layer = b / 768, tI = b % 768;
    K = 1024; N = 3072;
    W = attn_w + (size_t)layer * K * N; Wt = wt_attn + (size_t)layer * K * N;
    kx = tI % 16; ny = tI / 16;
  } else if (b < 3840) {          // proj: 3 layers x (16 x 16)
    b -= 3072; int layer = b / 256, tI = b % 256;
    K = 1024; N = 1024;
    W = proj_w + (size_t)layer * K * N; Wt = wt_proj + (size_t)layer * K * N;
    kx = tI % 16; ny = tI / 16;
  } else if (b < 6912) {          // fc: 3 layers x (16 x 64)
    b -= 3840; int layer = b / 1024, tI = b % 1024;
    K = 1024; N = 4096;
    W = fc_w + (size_t)layer * K * N; Wt = wt_fc + (size_t)layer * K * N;
    kx = tI % 16; ny = tI / 16;
  } else {                        // fcproj: 3 layers x (64 x 16)
    b -= 6912; int layer = b / 1024, tI = b % 1024;
    K = 4096; N = 1024;
    W = fcp_w + (size_t)layer * K * N; Wt = wt_fcp + (size_t)layer * K * N;
    kx = tI % 64; ny = tI / 64;
  }
  const int k0 = kx << 6, n0 = ny << 6;
  {
    const int r = tid >> 4, c4 = tid & 15;
#pragma unroll
    for (int p = 0; p < 4; ++p) {
      int kr = r + (p << 4);
      float4 v = *(const float4*)(W + (size_t)(k0 + kr) * N + n0 + (c4 << 2));
      tile[kr][(c4 << 2) + 0] = v.x;
      tile[kr][(c4 << 2) + 1] = v.y;
      tile[kr][(c4 << 2) + 2] = v.z;
      tile[kr][(c4 << 2) + 3] = v.w;
    }
  }
  __syncthreads();
  {
    const int n = tid >> 2, kq = tid & 3;
    bf16x8 o0, o1;
#pragma unroll
    for (int e = 0; e < 8; ++e) o0[e] = (short)f2bf(tile[(kq << 4) + e][n]);
#pragma unroll
    for (int e = 0; e < 8; ++e) o1[e] = (short)f2bf(tile[(kq << 4) + 8 + e][n]);
    unsigned short* dst = Wt + (size_t)(n0 + n) * K + k0 + (kq << 4);
    *(bf16x8*)dst = o0;
    *(bf16x8*)(dst + 8) = o1;
  }
}

// ---------------- fused reduce(bf16 partials) + layernorm ----------------
__global__ __launch_bounds__(256) void redln_k(float* __restrict__ x,
    const unsigned short* __restrict__ P, const float* __restrict__ bias,
    const float* __restrict__ lw, const float* __restrict__ lb,
    unsigned short* __restrict__ out, int splits)
{
  int row = blockIdx.x * 4 + (threadIdx.x >> 6);
  int lane = threadIdx.x & 63;
  const int c0 = lane * 16;
  float* xw = x + (size_t)row * CC + c0;
  float4 v[4];
#pragma unroll
  for (int i = 0; i < 4; ++i) v[i] = *(const float4*)(xw + i * 4);
  {
    const float4* b4 = (const float4*)(bias + c0);
#pragma unroll
    for (int i = 0; i < 4; ++i) {
      float4 bv = b4[i];
      v[i].x += bv.x; v[i].y += bv.y; v[i].z += bv.z; v[i].w += bv.w;
    }
  }
  for (int sp = 0; sp < splits; ++sp) {
    const unsigned short* pp = P + ((size_t)sp * 2048 + row) * CC + c0;
    bf16x8 pa = *(const bf16x8*)pp;
    bf16x8 pb = *(const bf16x8*)(pp + 8);
    v[0].x += bf2f((unsigned short)pa[0]); v[0].y += bf2f((unsigned short)pa[1]);
    v[0].z += bf2f((unsigned short)pa[2]); v[0].w += bf2f((unsigned short)pa[3]);
    v[1].x += bf2f((unsigned short)pa[4]); v[1].y += bf2f((unsigned short)pa[5]);
    v[1].z += bf2f((unsigned short)pa[6]); v[1].w += bf2f((unsigned short)pa[7]);
    v[2].x += bf2f((unsigned short)pb[0]); v[2].y += bf2f((unsigned short)pb[1]);
    v[2].z += bf2f((unsigned short)pb[2]); v[2].w += bf2f((unsigned short)pb[3]);
    v[3].x += bf2f((unsigned short)pb[4]); v[3].y += bf2f((unsigned short)pb[5]);
    v[3].z += bf2f((unsigned short)pb[6]); v[3].w += bf2f((unsigned short)pb[7]);
  }
  float s = 0.f, ss = 0.f;
#pragma unroll
  for (int i = 0; i < 4; ++i) {
    *(float4*)(xw + i * 4) = v[i];
    s  += v[i].x + v[i].y + v[i].z + v[i].w;
    ss += v[i].x*v[i].x + v[i].y*v[i].y + v[i].z*v[i].z + v[i].w*v[i].w;
  }
#pragma unroll
  for (int off = 1; off < 64; off <<= 1) {
    s  += __shfl_xor(s, off, 64);
    ss += __shfl_xor(ss, off, 64);
  }
  float mu = s * (1.f / CC);
  float var = ss * (1.f / CC) - mu * mu;
  float rstd = rsqrtf(var + 1e-5f);
  const float* wr = lw + c0;
  const float* br = lb + c0;
  unsigned q[8];
#pragma unroll
  for (int i = 0; i < 4; ++i) {
    float4 wv = *(const float4*)(wr + i * 4);
    float4 bv = *(const float4*)(br + i * 4);
    float o0 = (v[i].x - mu) * rstd * wv.x + bv.x;
    float o1 = (v[i].y - mu) * rstd * wv.y + bv.y;
    float o2 = (v[i].z - mu) * rstd * wv.z + bv.z;
    float o3 = (v[i].w - mu) * rstd * wv.w + bv.w;
    q[i*2+0] = pk2(o0, o1);
    q[i*2+1] = pk2(o2, o3);
  }
  uint4* op = (uint4*)(out + (size_t)row * CC + c0);
  op[0] = make_uint4(q[0], q[1], q[2], q[3]);
  op[1] = make_uint4(q[4], q[5], q[6], q[7]);
}

// ---------------- GEMM modes ----------------
#define MODE_QKV  0
#define MODE_PART 1
#define MODE_FC   2

// 64x128 tile GEMM: A panel 64 rows, B panel 128 rows, single 24KB LDS buffer,
// 2 barriers/K-step, 32x32x16 MFMA, chunk swizzle (kq ^= row&7, both sides).
// Each wave computes a 32-row x 64-col strip (2 x f32x16 acc).
template<int MODE>
__global__ __launch_bounds__(256, 4) void gemm_k(
    const unsigned short* __restrict__ A,
    const unsigned short* __restrict__ Wt,
    const float* __restrict__ bias,
    unsigned short* __restrict__ obf,
    unsigned short* __restrict__ q_o,
    unsigned short* __restrict__ k_o,
    unsigned short* __restrict__ v_o,
    int M, int N, int K, int kchunk, int ncol0)
{
  __shared__ alignas(16) unsigned short Asm[64 * 64];    // 8 KB
  __shared__ alignas(16) unsigned short Bsm[128 * 64];   // 16 KB
  const int tid  = threadIdx.x;
  const int wave = tid >> 6, lane = tid & 63;
  const int rl = lane & 31, hi = lane >> 5;
  const int nTM = M >> 6, nTN = N >> 7;
  int bid = blockIdx.x;
  const int mt = bid % nTM; bid /= nTM;
  const int nt = bid % nTN;
  const int s  = bid / nTN;
  const int m0 = mt << 6, n0 = nt << 7;
  const int kb = s * kchunk;
  const int nIter = kchunk >> 6;
  const int wm = (wave >> 1) << 5, wn = (wave & 1) << 6;
  f32x16 acc[2] = {};

  // staging: 24 segments of 64 granules; segs 0-7 = A (64 rows), 8-23 = B (128 rows)
#define STAGE(K0)                                                             \
  {                                                                           \
    _Pragma("unroll")                                                         \
    for (int c = 0; c < 6; ++c) {                                             \
      const int seg = wave * 6 + c;                                           \
      if (seg < 8) {                                                          \
        const int g = (seg << 6) + lane;                                      \
        const int row = g >> 3, kq = g & 7;                                   \
        const int kqs = kq ^ (row & 7);                                       \
        const unsigned short* asrc = A + (size_t)(m0 + row) * K + (K0) + (kqs << 3); \
        __builtin_amdgcn_global_load_lds(GPTR(asrc), LPTR(&Asm[g << 3]), 16, 0, 0);  \
      } else {                                                                \
        const int g = ((seg - 8) << 6) + lane;                                \
        const int row = g >> 3, kq = g & 7;                                   \
        const int kqs = kq ^ (row & 7);                                       \
        const unsigned short* bsrc = Wt + (size_t)(n0 + row) * K + (K0) + (kqs << 3); \
        __builtin_amdgcn_global_load_lds(GPTR(bsrc), LPTR(&Bsm[g << 3]), 16, 0, 0);  \
      }                                                                       \
    }                                                                         \
  }

  for (int t = 0; t < nIter; ++t) {
    STAGE(kb + (t << 6));
    __syncthreads();                     // vmcnt(0) drain + barrier
#pragma unroll
    for (int sl = 0; sl < 4; ++sl) {
      const int c = sl * 2 + hi;                 // 16B chunk index within row
      const int cs = (c ^ (rl & 7)) << 3;        // swizzled element offset
      bf16x8 a0 = *(const bf16x8*)(Asm + ((wm + rl) << 6) + cs);
      bf16x8 b0 = *(const bf16x8*)(Bsm + ((wn + rl) << 6) + cs);
      bf16x8 b1 = *(const bf16x8*)(Bsm + ((wn + 32 + rl) << 6) + cs);
      acc[0] = mfma32_bf16(a0, b0, acc[0]);
      acc[1] = mfma32_bf16(a0, b1, acc[1]);
    }
    __syncthreads();                     // all waves done reading before restage
  }
#undef STAGE

  // C/D layout: col = lane&31, row = (reg&3) + 8*(reg>>2) + 4*(lane>>5)
#pragma unroll
  for (int j = 0; j < 2; ++j) {
    int gc = n0 + wn + j * 32 + rl;
    int gcol = ncol0 + gc;
    float bv = (MODE == MODE_PART) ? 0.f : bias[gcol];
    int gr0 = m0 + wm + 4 * hi;
#pragma unroll
    for (int reg = 0; reg < 16; ++reg) {
      int grow = gr0 + (reg & 3) + 8 * (reg >> 2);
      float val = acc[j][reg] + bv;
      if (MODE == MODE_QKV) {
        int which = gcol >> 10;
        int head = (gcol >> 6) & 15;
        int d = gcol & 63;
        int bb = grow >> 10, tt2 = grow & (TT - 1);
        size_t bhb = ((size_t)((bb << 4) + head)) << 16;
        if (which == 2)      v_o[bhb + ((size_t)d << 10) + tt2] = f2bf(val);
        else if (which == 1) k_o[bhb + ((size_t)tt2 << 6) + d] = f2bf(val);
        else                 q_o[bhb + ((size_t)tt2 << 6) + d] = f2bf(val);
      } else if (MODE == MODE_FC) {
        val = (val >= 0.f) ? val : 0.01f * val;
        obf[(size_t)grow * N + gc] = f2bf(val);
      } else {  // MODE_PART: bf16 partials
        obf[((size_t)s * M + grow) * N + gc] = f2bf(val);
      }
    }
  }
}

// ---------------- flash attention (causal), layers 0-2 ----------------
// 128-key tiles; T13 defer-rescale; V^T input.
__global__ __launch_bounds__(256) void attn_k(
    const unsigned short* __restrict__ Qb,
    const unsigned short* __restrict__ Kb,
    const unsigned short* __restrict__ Vb,   // [bh][d][t]
    unsigned short* __restrict__ ybuf)
{
  __shared__ alignas(16) unsigned short Ksm[128][72];
  __shared__ alignas(16) unsigned short Vtsm[64][128];
  __shared__ alignas(16) unsigned short Psm[4][16][136];
  const int tid = threadIdx.x;
  const int wave = tid >> 6, lane = tid & 63;
  const int lg = lane >> 4, ll = lane & 15;
  const int qt = blockIdx.x & 15, bh = blockIdx.x >> 4;
  const int b = bh >> 4, h = bh & 15;
  const size_t base = (size_t)bh << 16;
  const int q0 = qt << 6;
  const float SC = 0.125f * 1.44269504f;

  const int qrow = q0 + wave * 16 + ll;
  bf16x8 aq0 = *(const bf16x8*)(Qb + base + ((size_t)qrow << 6) + (lg << 3));
  bf16x8 aq1 = *(const bf16x8*)(Qb + base + ((size_t)qrow << 6) + 32 + (lg << 3));

  f32x4 accy[4] = {};
  float m_run[4], l_run[4];
#pragma unroll
  for (int r = 0; r < 4; ++r) { m_run[r] = -1e30f; l_run[r] = 0.f; }

  const int sk_row = tid >> 3, sk_cq = tid & 7;
  const int sv_d = tid & 63, sv_kq0 = tid >> 6;
  const int qg0 = q0 + wave * 16 + (lg << 2);

  for (int kbase = 0; kbase < q0 + 64; kbase += 128) {
#pragma unroll
    for (int p = 0; p < 4; ++p) {
      int r = sk_row + (p << 5);
      bf16x8 kv = *(const bf16x8*)(Kb + base + ((size_t)(kbase + r) << 6) + (sk_cq << 3));
      *(bf16x8*)&Ksm[r][sk_cq << 3] = kv;
    }
#pragma unroll
    for (int p = 0; p < 4; ++p) {
      int kq8 = sv_kq0 + (p << 2);
      bf16x8 wv = *(const bf16x8*)(Vb + base + ((size_t)sv_d << 10) + kbase + (kq8 << 3));
      int u = kq8 ^ (sv_d & 7);
      *(bf16x8*)&Vtsm[sv_d][u << 3] = wv;
    }
    __syncthreads();

    int kkmax = ((q0 + 63 - kbase) >> 4) + 1;
    if (kkmax > 8) kkmax = 8;
    const int kkmax2 = (kkmax + 1) & ~1;
    const int jmax = kkmax2 >> 1;

    float p_[8][4];
    float rmax[4] = {-1e30f, -1e30f, -1e30f, -1e30f};
    __builtin_amdgcn_s_setprio(1);
#pragma unroll
    for (int kk = 0; kk < 8; ++kk) {
      if (kk < kkmax) {
        f32x4 z = {};
        bf16x8 bk0 = *(const bf16x8*)&Ksm[kk * 16 + ll][lg << 3];
        bf16x8 bk1 = *(const bf16x8*)&Ksm[kk * 16 + ll][32 + (lg << 3)];
        z = mfma_bf16(aq0, bk0, z);
        z = mfma_bf16(aq1, bk1, z);
        int key = kbase + kk * 16 + ll;
#pragma unroll
        for (int r = 0; r < 4; ++r) {
          float v = z[r] * SC;
          v = (key > qg0 + r) ? -1e30f : v;
          p_[kk][r] = v;
          rmax[r] = fmaxf(rmax[r], v);
        }
      } else {
#pragma unroll
        for (int r = 0; r < 4; ++r) p_[kk][r] = -1e30f;
      }
    }
    __builtin_amdgcn_s_setprio(0);
#pragma unroll
    for (int off = 1; off < 16; off <<= 1)
#pragma unroll
      for (int r = 0; r < 4; ++r)
        rmax[r] = fmaxf(rmax[r], __shfl_xor(rmax[r], off, 64));

    int ok = (rmax[0] <= m_run[0] + 8.f) & (rmax[1] <= m_run[1] + 8.f) &
             (rmax[2] <= m_run[2] + 8.f) & (rmax[3] <= m_run[3] + 8.f);
    const int skip = __all(ok);
    float alpha[4];
    if (!skip) {
#pragma unroll
      for (int r = 0; r < 4; ++r) {
        float mn = fmaxf(m_run[r], rmax[r]);
        alpha[r] = exp2f(m_run[r] - mn);
        m_run[r] = mn;
      }
    }
    float rsum[4] = {0.f, 0.f, 0.f, 0.f};
#pragma unroll
    for (int kk = 0; kk < 8; ++kk)
#pragma unroll
      for (int r = 0; r < 4; ++r) {
        float e = exp2f(p_[kk][r] - m_run[r]);
        p_[kk][r] = e;
        rsum[r] += e;
      }
#pragma unroll
    for (int off = 1; off < 16; off <<= 1)
#pragma unroll
      for (int r = 0; r < 4; ++r)
        rsum[r] += __shfl_xor(rsum[r], off, 64);
    if (!skip) {
#pragma unroll
      for (int r = 0; r < 4; ++r)
        l_run[r] = l_run[r] * alpha[r] + rsum[r];
#pragma unroll
      for (int df = 0; df < 4; ++df)
#pragma unroll
        for (int r = 0; r < 4; ++r)
          accy[df][r] *= alpha[r];
    } else {
#pragma unroll
      for (int r = 0; r < 4; ++r)
        l_run[r] += rsum[r];
    }

#pragma unroll
    for (int kk = 0; kk < 8; ++kk)
      if (kk < kkmax2)
#pragma unroll
        for (int r = 0; r < 4; ++r)
          Psm[wave][(lg << 2) + r][kk * 16 + ll] = f2bf(p_[kk][r]);

    __builtin_amdgcn_s_setprio(1);
#pragma unroll
    for (int j = 0; j < 4; ++j) {
      if (j < jmax) {
        bf16x8 pa = *(const bf16x8*)&Psm[wave][ll][j * 32 + (lg << 3)];
#pragma unroll
        for (int df = 0; df < 4; ++df) {
          int d = df * 16 + ll;
          int u = ((j << 2) + lg) ^ (d & 7);
          bf16x8 bv = *(const bf16x8*)&Vtsm[d][u << 3];
          accy[df] = mfma_bf16(pa, bv, accy[df]);
        }
      }
    }
    __builtin_amdgcn_s_setprio(0);
    __syncthreads();
  }

#pragma unroll
  for (int df = 0; df < 4; ++df)
#pragma unroll
    for (int r = 0; r < 4; ++r) {
      int qr = qg0 + r;
      float y = accy[df][r] / l_run[r];
      ybuf[(((size_t)((b << 10) + qr)) << 10) + (h << 6) + df * 16 + ll] = f2bf(y);
    }
}

// ---------------- layer-3 tail (last position only; all k-slab parallel) ----------------

__global__ __launch_bounds__(256) void qlast_k(
    const unsigned short* __restrict__ hbuf,
    const float* __restrict__ Wq,
    float* __restrict__ qpart)
{
  __shared__ float xs[2][128];
  const int tid = threadIdx.x, ks = blockIdx.y;
  {
    const int b = tid >> 7, j = tid & 127;
    xs[b][j] = bf2f(hbuf[((size_t)(b * TT + TT - 1)) * CC + ks * 128 + j]);
  }
  __syncthreads();
  const int n = blockIdx.x * 256 + tid;
  float a0 = 0.f, a1 = 0.f;
  const float* wp = Wq + (size_t)(ks * 128) * 3072 + n;
  for (int k = 0; k < 128; k += 8)
#pragma unroll
    for (int u = 0; u < 8; ++u) {
      float w = wp[(size_t)(k + u) * 3072];
      a0 += xs[0][k + u] * w;
      a1 += xs[1][k + u] * w;
    }
  qpart[(size_t)(ks * 2 + 0) * 1024 + n] = a0;
  qpart[(size_t)(ks * 2 + 1) * 1024 + n] = a1;
}

__global__ __launch_bounds__(256) void attnlast2_k(
    const float* __restrict__ qpart, const float* __restrict__ bq,
    const unsigned short* __restrict__ Kb,
    const unsigned short* __restrict__ Vb,   // [bh][d][t]
    float* __restrict__ y_last)
{
  __shared__ float qs[64];
  __shared__ float wm[4], wl[4], wacc[4][64];
  const int tid = threadIdx.x;
  const int wave = tid >> 6, lane = tid & 63;
  const int bh = blockIdx.x;
  const int b = bh >> 4, h = bh & 15;
  const size_t base = (size_t)bh << 16;
  if (tid < 64) {
    const int col = h * 64 + tid;
    float q = bq[col];
#pragma unroll
    for (int ks = 0; ks < 8; ++ks)
      q += qpart[(size_t)(ks * 2 + b) * 1024 + col];
    qs[tid] = q;
  }
  __syncthreads();

  float m_w = -1e30f, l_w = 0.f, acc = 0.f;
  for (int ks = 0; ks < 4; ++ks) {
    const int key = ks * 256 + wave * 64 + lane;
    float s = 0.f;
    const unsigned short* kp = Kb + base + ((size_t)key << 6);
#pragma unroll
    for (int o = 0; o < 8; ++o) {
      bf16x8 kv = *(const bf16x8*)(kp + (o << 3));
#pragma unroll
      for (int e = 0; e < 8; ++e)
        s += qs[(o << 3) + e] * bf2f((unsigned short)kv[e]);
    }
    s *= 0.125f;
    float m = s;
#pragma unroll
    for (int off = 1; off < 64; off <<= 1)
      m = fmaxf(m, __shfl_xor(m, off, 64));
    float mn = fmaxf(m_w, m);
    float alpha = __expf(m_w - mn);
    m_w = mn;
    float p = __expf(s - mn);
    float ps = p;
#pragma unroll
    for (int off = 1; off < 64; off <<= 1)
      ps += __shfl_xor(ps, off, 64);
    l_w = l_w * alpha + ps;
    float a2 = 0.f;
    const unsigned short* vp = Vb + base + ((size_t)lane << 10) + ks * 256 + wave * 64;
#pragma unroll
    for (int j8 = 0; j8 < 8; ++j8) {
      bf16x8 vv = *(const bf16x8*)(vp + (j8 << 3));
#pragma unroll
      for (int e = 0; e < 8; ++e) {
        float pj = __shfl(p, (j8 << 3) + e, 64);
        a2 += pj * bf2f((unsigned short)vv[e]);
      }
    }
    acc = acc * alpha + a2;
  }
  if (lane == 0) { wm[wave] = m_w; wl[wave] = l_w; }
  wacc[wave][lane] = acc;
  __syncthreads();
  if (wave == 0) {
    float m0 = fmaxf(fmaxf(wm[0], wm[1]), fmaxf(wm[2], wm[3]));
    float lt = 0.f, at = 0.f;
#pragma unroll
    for (int sI = 0; sI < 4; ++sI) {
      float f = __expf(wm[sI] - m0);
      lt += wl[sI] * f;
      at += wacc[sI][lane] * f;
    }
    y_last[b * CC + h * 64 + lane] = at / lt;
  }
}

__global__ __launch_bounds__(256) void projpart_k(
    const float* __restrict__ ylast,
    const float* __restrict__ W,
    float* __restrict__ ppart)
{
  __shared__ float xs[2][128];
  const int tid = threadIdx.x, ks = blockIdx.y;
  {
    const int b = tid >> 7, j = tid & 127;
    xs[b][j] = ylast[b * 1024 + ks * 128 + j];
  }
  __syncthreads();
  const int n = blockIdx.x * 256 + tid;
  float a0 = 0.f, a1 = 0.f;
  const float* wp = W + (size_t)(ks * 128) * 1024 + n;
  for (int k = 0; k < 128; k += 8)
#pragma unroll
    for (int u = 0; u < 8; ++u) {
      float w = wp[(size_t)(k + u) * 1024];
      a0 += xs[0][k + u] * w;
      a1 += xs[1][k + u] * w;
    }
  ppart[(size_t)(ks * 2 + 0) * 1024 + n] = a0;
  ppart[(size_t)(ks * 2 + 1) * 1024 + n] = a1;
}

__global__ __launch_bounds__(256) void fclast_k(
    const float* __restrict__ x, const float* __restrict__ ppart,
    const float* __restrict__ pbias,
    const float* __restrict__ lw, const float* __restrict__ lb,
    const float* __restrict__ W,
    float* __restrict__ fcpart)
{
  __shared__ float xs[2][1024];
  const int tid = threadIdx.x;
  const int wave = tid >> 6, lane = tid & 63;
  if (wave < 2) {
    const int c0 = lane * 16;
    const float* xr = x + ((size_t)(wave * TT + TT - 1)) * CC + c0;
    float4 v[4];
    float s = 0.f, ss = 0.f;
#pragma unroll
    for (int i = 0; i < 4; ++i) {
      v[i] = *(const float4*)(xr + i * 4);
      float4 bv = *(const float4*)(pbias + c0 + i * 4);
      v[i].x += bv.x; v[i].y += bv.y; v[i].z += bv.z; v[i].w += bv.w;
    }
#pragma unroll
    for (int sp = 0; sp < 8; ++sp) {
      const float* pp = ppart + (size_t)(sp * 2 + wave) * 1024 + c0;
#pragma unroll
      for (int i = 0; i < 4; ++i) {
        float4 pv = *(const float4*)(pp + i * 4);
        v[i].x += pv.x; v[i].y += pv.y; v[i].z += pv.z; v[i].w += pv.w;
      }
    }
#pragma unroll
    for (int i = 0; i < 4; ++i) {
      s  += v[i].x + v[i].y + v[i].z + v[i].w;
      ss += v[i].x*v[i].x + v[i].y*v[i].y + v[i].z*v[i].z + v[i].w*v[i].w;
    }
#pragma unroll
    for (int off = 1; off < 64; off <<= 1) {
      s  += __shfl_xor(s, off, 64);
      ss += __shfl_xor(ss, off, 64);
    }
    float mu = s * (1.f / CC);
    float var = ss * (1.f / CC) - mu * mu;
    float rstd = rsqrtf(var + 1e-5f);
#pragma unroll
    for (int i = 0; i < 4; ++i) {
      float4 wv = *(const float4*)(lw + c0 + i * 4);
      float4 bv = *(const float4*)(lb + c0 + i * 4);
      xs[wave][c0 + i * 4 + 0] = (v[i].x - mu) * rstd * wv.x + bv.x;
      xs[wave][c0 + i * 4 + 1] = (v[i].y - mu) * rstd * wv.y + bv.y;
      xs[wave][c0 + i * 4 + 2] = (v[i].z - mu) * rstd * wv.z + bv.z;
      xs[wave][c0 + i * 4 + 3] = (v[i].w - mu) * rstd * wv.w + bv.w;
    }
  }
  __syncthreads();
  const int ks = blockIdx.y;
  const int n = blockIdx.x * 256 + tid;
  float a0 = 0.f, a1 = 0.f;
  const float* wp = W + (size_t)(ks * 128) * 4096 + n;
  for (int k = 0; k < 128; k += 8)
#pragma unroll
    for (int u = 0; u < 8; ++u) {
      float w = wp[(size_t)(k + u) * 4096];
      a0 += xs[0][ks * 128 + k + u] * w;
      a1 += xs[1][ks * 128 + k + u] * w;
    }
  fcpart[(size_t)(ks * 2 + 0) * 4096 + n] = a0;
  fcpart[(size_t)(ks * 2 + 1) * 4096 + n] = a1;
}

__global__ __launch_bounds__(256) void fcprojpart_k(
    const float* __restrict__ fcpart, const float* __restrict__ fcbias,
    const float* __restrict__ W,
    float* __restrict__ fppart)
{
  __shared__ float hs[2][512];
  const int tid = threadIdx.x, ks = blockIdx.y;
#pragma unroll
  for (int i = 0; i < 4; ++i) {
    const int e = tid + 256 * i;
    const int b = e >> 9, j = e & 511;
    const int c = ks * 512 + j;
    float v = fcbias[c];
#pragma unroll
    for (int sp = 0; sp < 8; ++sp)
      v += fcpart[(size_t)(sp * 2 + b) * 4096 + c];
    hs[b][j] = (v >= 0.f) ? v : 0.01f * v;
  }
  __syncthreads();
  const int n = blockIdx.x * 256 + tid;
  float a0 = 0.f, a1 = 0.f;
  const float* wp = W + (size_t)(ks * 512) * 1024 + n;
  for (int k = 0; k < 512; k += 8)
#pragma unroll
    for (int u = 0; u < 8; ++u) {
      float w = wp[(size_t)(k + u) * 1024];
      a0 += hs[0][k + u] * w;
      a1 += hs[1][k + u] * w;
    }
  fppart[(size_t)(ks * 2 + 0) * 1024 + n] = a0;
  fppart[(size_t)(ks * 2 + 1) * 1024 + n] = a1;
}

__global__ __launch_bounds__(256) void lnfmerge_k(const float* __restrict__ x,
    const float* __restrict__ ppart, const float* __restrict__ pbias,
    const float* __restrict__ fppart, const float* __restrict__ fpbias,
    const float* __restrict__ lw, const float* __restrict__ lb,
    float* __restrict__ xf)
{
  __shared__ float rs[4], rss[4];
  const int row = blockIdx.x;
  const int tid = threadIdx.x;
  const int wave = tid >> 6, lane = tid & 63;
  const int c0 = tid * 4;
  float4 v = *(const float4*)(x + ((size_t)(row * TT + TT - 1)) * CC + c0);
  {
    float4 b1 = *(const float4*)(pbias + c0);
    float4 b2 = *(const float4*)(fpbias + c0);
    v.x += b1.x + b2.x; v.y += b1.y + b2.y;
    v.z += b1.z + b2.z; v.w += b1.w + b2.w;
  }
#pragma unroll
  for (int sp = 0; sp < 8; ++sp) {
    float4 a = *(const float4*)(ppart + (size_t)(sp * 2 + row) * 1024 + c0);
    float4 b = *(const float4*)(fppart + (size_t)(sp * 2 + row) * 1024 + c0);
    v.x += a.x + b.x; v.y += a.y + b.y;
    v.z += a.z + b.z; v.w += a.w + b.w;
  }
  float s  = v.x + v.y + v.z + v.w;
  float ss = v.x*v.x + v.y*v.y + v.z*v.z + v.w*v.w;
#pragma unroll
  for (int off = 1; off < 64; off <<= 1) {
    s  += __shfl_xor(s, off, 64);
    ss += __shfl_xor(ss, off, 64);
  }
  if (lane == 0) { rs[wave] = s; rss[wave] = ss; }
  __syncthreads();
  s  = rs[0] + rs[1] + rs[2] + rs[3];
  ss = rss[0] + rss[1] + rss[2] + rss[3];
  float mu = s * (1.f / CC);
  float var = ss * (1.f / CC) - mu * mu;
  float rstd = rsqrtf(var + 1e-5f);
  float4 wv = *(const float4*)(lw + c0);
  float4 bv = *(const float4*)(lb + c0);
  float4 o;
  o.x = (v.x - mu) * rstd * wv.x + bv.x;
  o.y = (v.y - mu) * rstd * wv.y + bv.y;
  o.z = (v.z - mu) * rstd * wv.z + bv.z;
  o.w = (v.w - mu) * rstd * wv.w + bv.w;
  *(float4*)(xf + (size_t)row * CC + c0) = o;
}

// ---------------- lm_head ----------------
__global__ __launch_bounds__(256) void head_k(const float* __restrict__ xf,
    const float* __restrict__ wte, float* __restrict__ out)
{
  int v = (blockIdx.x << 2) + (threadIdx.x >> 6);
  if (v >= VOCAB) return;
  int lane = threadIdx.x & 63;
  const float4* wr = (const float4*)(wte + (size_t)v * CC);
  const float4* x0 = (const float4*)xf;
  const float4* x1 = (const float4*)(xf + CC);
  float a0 = 0.f, a1 = 0.f;
#pragma unroll
  for (int i = 0; i < 4; ++i) {
    float4 wv = wr[lane + i * 64];
    float4 p0 = x0[lane + i * 64];
    float4 p1 = x1[lane + i * 64];
    a0 += wv.x * p0.x + wv.y * p0.y + wv.z * p0.z + wv.w * p0.w;
    a1 += wv.x * p1.x + wv.y * p1.y + wv.z * p1.z + wv.w * p1.w;
  }
#pragma unroll
  for (int off = 1; off < 64; off <<= 1) {
    a0 += __shfl_xor(a0, off, 64);
    a1 += __shfl_xor(a1, off, 64);
  }
  if (lane == 0) {
    out[v] = a0;
    out[VOCAB + v] = a1;
  }
}

// ---------------- host orchestration ----------------
extern "C" void kernel_launch(void* const* d_in, const int* in_sizes, int n_in,
                              void* d_out, int out_size, void* d_ws, size_t ws_size,
                              hipStream_t stream)
{
  const int*   idx      = (const int*)d_in[0];
  const float* wte      = (const float*)d_in[1];
  const float* wpe      = (const float*)d_in[2];
  const float* ln1_w    = (const float*)d_in[3];
  const float* ln1_b    = (const float*)d_in[4];
  const float* attn_w   = (const float*)d_in[5];
  const float* attn_b   = (const float*)d_in[6];
  const float* proj_w   = (const float*)d_in[7];
  const float* proj_b   = (const float*)d_in[8];
  const float* ln2_w    = (const float*)d_in[9];
  const float* ln2_b    = (const float*)d_in[10];
  const float* fc_w     = (const float*)d_in[11];
  const float* fc_b     = (const float*)d_in[12];
  const float* fcproj_w = (const float*)d_in[13];
  const float* fcproj_b = (const float*)d_in[14];
  const float* lnf_w    = (const float*)d_in[15];
  const float* lnf_b    = (const float*)d_in[16];
  float* out = (float*)d_out;

  const size_t MB = 1u << 20;
  char* ws = (char*)d_ws;
  float*          x   = (float*)ws;                       // 8 MiB
  unsigned short* h   = (unsigned short*)(ws + 8*MB);     // 4 MiB
  unsigned short* qb  = (unsigned short*)(ws + 12*MB);    // 4 MiB
  unsigned short* kb_ = (unsigned short*)(ws + 16*MB);    // 4 MiB
  unsigned short* vb  = (unsigned short*)(ws + 20*MB);    // 4 MiB (V^T)
  unsigned short* yb  = (unsigned short*)(ws + 24*MB);    // 4 MiB
  unsigned short* hf  = (unsigned short*)(ws + 28*MB);    // 16 MiB
  char* sm = ws + 44*MB;
  float* xf     = (float*)(sm + 0);
  float* ylast  = (float*)(sm + 16*1024);
  float* qpart  = (float*)(sm + 64*1024);
  float* ppart  = (float*)(sm + 128*1024);
  float* fppart = (float*)(sm + 192*1024);
  float* fcpart = (float*)(sm + 256*1024);
  unsigned short* wt_attn   = (unsigned short*)(ws + 46*MB);
  unsigned short* wt_proj   = (unsigned short*)(ws + 70*MB);
  unsigned short* wt_fc     = (unsigned short*)(ws + 76*MB);
  unsigned short* wt_fcproj = (unsigned short*)(ws + 100*MB);
  unsigned short* Ppart     = (unsigned short*)(ws + 124*MB);

  prep_k<<<2048 + 9984, 256, 0, stream>>>(idx, wte, wpe, ln1_w, ln1_b, x, h,
      attn_w, wt_attn, proj_w, wt_proj, fc_w, wt_fc, fcproj_w, wt_fcproj);

  for (int l = 0; l < 3; ++l) {
    gemm_k<MODE_QKV><<<32 * 24, 256, 0, stream>>>(h,
        wt_attn + (size_t)l * 3072 * 1024, attn_b + (size_t)l * 3 * CC,
        nullptr, qb, kb_, vb, 2048, 3072, 1024, 1024, 0);
    attn_k<<<NBATCH * NHEAD * 16, 256, 0, stream>>>(qb, kb_, vb, yb);
    gemm_k<MODE_PART><<<32 * 8 * 4, 256, 0, stream>>>(yb,
        wt_proj + (size_t)l * 1024 * 1024, nullptr,
        Ppart, nullptr, nullptr, nullptr, 2048, 1024, 1024, 256, 0);
    redln_k<<<512, 256, 0, stream>>>(x, Ppart, proj_b + l * CC,
        ln2_w + l * CC, ln2_b + l * CC, h, 4);
    gemm_k<MODE_FC><<<32 * 32, 256, 0, stream>>>(h,
        wt_fc + (size_t)l * 1024 * 4096, fc_b + (size_t)l * 4 * CC,
        hf, nullptr, nullptr, nullptr, 2048, 4096, 1024, 1024, 0);
    gemm_k<MODE_PART><<<32 * 8 * 4, 256, 0, stream>>>(hf,
        wt_fcproj + (size_t)l * 4096 * 1024, nullptr,
        Ppart, nullptr, nullptr, nullptr, 2048, 1024, 4096, 1024, 0);
    redln_k<<<512, 256, 0, stream>>>(x, Ppart, fcproj_b + l * CC,
        ln1_w + (l + 1) * CC, ln1_b + (l + 1) * CC, h, 4);
  }

  // ---- layer 3: K/V for all positions, everything else last-position only ----
  {
    const int l = 3;
    gemm_k<MODE_QKV><<<32 * 16, 256, 0, stream>>>(h,
        wt_attn + (size_t)l * 3072 * 1024 + (size_t)1024 * 1024,
        attn_b + (size_t)l * 3 * CC,
        nullptr, qb, kb_, vb, 2048, 2048, 1024, 1024, 1024);
    qlast_k<<<dim3(4, 8), 256, 0, stream>>>(h,
        attn_w + (size_t)l * CC * 3 * CC, qpart);
    attnlast2_k<<<32, 256, 0, stream>>>(qpart, attn_b + (size_t)l * 3 * CC,
        kb_, vb, ylast);
    projpart_k<<<dim3(4, 8), 256, 0, stream>>>(ylast,
        proj_w + (size_t)l * CC * CC, ppart);
    fclast_k<<<dim3(16, 8), 256, 0, stream>>>(x, ppart, proj_b + l * CC,
        ln2_w + l * CC, ln2_b + l * CC,
        fc_w + (size_t)l * CC * 4 * CC, fcpart);
    fcprojpart_k<<<dim3(4, 8), 256, 0, stream>>>(fcpart,
        fc_b + (size_t)l * 4 * CC, fcproj_w + (size_t)l * 4 * CC * CC, fppart);
    lnfmerge_k<<<2, 256, 0, stream>>>(x, ppart, proj_b + l * CC,
        fppart, fcproj_b + l * CC, lnf_w, lnf_b, xf);
  }

  head_k<<<(VOCAB + 3) / 4, 256, 0, stream>>>(xf, wte, out);
}

// Round 16
// 638.218 us; speedup vs baseline: 1.0093x; 1.0093x over previous
//
#include <hip/hip_runtime.h>
#include <hip/hip_bf16.h>

// GPT-2-ish forward: L=4, B=2, T=1024, C=1024, H=16, D=64, V=50257.
// Round 16: revert GEMM to round-14 config (128x128 tile, 32x32x16 MFMA,
// single 32KB buffer, chunk swizzle) — measured best. proj split-K 4 -> 2
// (halves partial traffic). Attention/tail/prep frozen from round 14.

#define TT 1024
#define CC 1024
#define NHEAD 16
#define DHEAD 64
#define NBATCH 2
#define VOCAB 50257

typedef __attribute__((ext_vector_type(8))) short bf16x8;
typedef __attribute__((ext_vector_type(4))) float f32x4;
typedef __attribute__((ext_vector_type(16))) float f32x16;

#define GPTR(p) (const __attribute__((address_space(1))) void*)(p)
#define LPTR(p) (__attribute__((address_space(3))) void*)(p)

__device__ __forceinline__ unsigned short f2bf(float f) {
  union { float f; unsigned u; } v; v.f = f;
  unsigned r = v.u + 0x7fffu + ((v.u >> 16) & 1u);   // RNE
  return (unsigned short)(r >> 16);
}
__device__ __forceinline__ float bf2f(unsigned short u) {
  union { unsigned u; float f; } v; v.u = ((unsigned)u) << 16;
  return v.f;
}

__device__ __forceinline__ f32x4 mfma_bf16(bf16x8 a, bf16x8 b, f32x4 c) {
  return __builtin_amdgcn_mfma_f32_16x16x32_bf16(a, b, c, 0, 0, 0);
}
__device__ __forceinline__ f32x16 mfma32_bf16(bf16x8 a, bf16x8 b, f32x16 c) {
  return __builtin_amdgcn_mfma_f32_32x32x16_bf16(a, b, c, 0, 0, 0);
}

__device__ __forceinline__ unsigned pk2(float lo, float hi) {
  return (unsigned)f2bf(lo) | ((unsigned)f2bf(hi) << 16);
}

// ---------------- prep: embedding+LN (blocks 0..2047) + weight convert ----------------
__global__ __launch_bounds__(256) void prep_k(const int* __restrict__ idx,
    const float* __restrict__ wte, const float* __restrict__ wpe,
    const float* __restrict__ lw, const float* __restrict__ lb,
    float* __restrict__ x, unsigned short* __restrict__ h,
    const float* __restrict__ attn_w, unsigned short* __restrict__ wt_attn,
    const float* __restrict__ proj_w, unsigned short* __restrict__ wt_proj,
    const float* __restrict__ fc_w,   unsigned short* __restrict__ wt_fc,
    const float* __restrict__ fcp_w,  unsigned short* __restrict__ wt_fcp)
{
  __shared__ float tile[64][65];
  const int tid = threadIdx.x;
  if (blockIdx.x < 2048) {
    const int row = blockIdx.x;
    const int t = row & (TT - 1);
    const int tok = idx[row];
    const int wave = tid >> 6, lane = tid & 63;
    float4 va = ((const float4*)(wte + (size_t)tok * CC))[tid];
    float4 vp = ((const float4*)(wpe + (size_t)t * CC))[tid];
    float4 v = make_float4(va.x + vp.x, va.y + vp.y, va.z + vp.z, va.w + vp.w);
    ((float4*)(x + (size_t)row * CC))[tid] = v;
    float s  = v.x + v.y + v.z + v.w;
    float ss = v.x*v.x + v.y*v.y + v.z*v.z + v.w*v.w;
#pragma unroll
    for (int off = 1; off < 64; off <<= 1) {
      s  += __shfl_xor(s, off, 64);
      ss += __shfl_xor(ss, off, 64);
    }
    if (lane == 0) { tile[0][wave] = s; tile[0][4 + wave] = ss; }
    __syncthreads();
    s  = tile[0][0] + tile[0][1] + tile[0][2] + tile[0][3];
    ss = tile[0][4] + tile[0][5] + tile[0][6] + tile[0][7];
    float mu = s * (1.f / CC);
    float var = ss * (1.f / CC) - mu * mu;
    float rstd = rsqrtf(var + 1e-5f);
    float4 wv = ((const float4*)lw)[tid];
    float4 bv = ((const float4*)lb)[tid];
    float o0 = (v.x - mu) * rstd * wv.x + bv.x;
    float o1 = (v.y - mu) * rstd * wv.y + bv.y;
    float o2 = (v.z - mu) * rstd * wv.z + bv.z;
    float o3 = (v.w - mu) * rstd * wv.w + bv.w;
    ((uint2*)(h + (size_t)row * CC))[tid] = make_uint2(pk2(o0, o1), pk2(o2, o3));
    return;
  }
  int b = blockIdx.x - 2048;
  const float* W; unsigned short* Wt; int K, N, kx, ny;
  if (b < 3072) {                 // attn: 4 layers x (16 x 48)
    int layer = b / 768, tI = b % 768;
    K = 1024; N = 3072;
    W = attn_w + (size_t)layer * K * N; Wt = wt_attn + (size_t)layer * K * N;
    kx = tI % 16; ny = tI / 16;
  } else if (b < 3840) {          // proj: 3 layers x (16 x 16)
    b -= 3072; int layer = b / 256, tI = b % 256;
    K = 1024; N = 1024;
    W = proj_w + (size_t)layer * K * N; Wt = wt_proj + (size_t)layer * K * N;
    kx = tI % 16; ny = tI / 16;
  } else if (b < 6912) {          // fc: 3 layers x (16 x 64)
    b -= 3840; int layer = b / 1024, tI = b % 1024;
    K = 1024; N = 4096;
    W = fc_w + (size_t)layer * K * N; Wt = wt_fc + (size_t)layer * K * N;
    kx = tI % 16; ny = tI / 16;
  } else {                        // fcproj: 3 layers x (64 x 16)
    b -= 6912; int layer = b / 1024, tI = b % 1024;
    K = 4096; N = 1024;
    W = fcp_w + (size_t)layer * K * N; Wt = wt_fcp + (size_t)layer * K * N;
    kx = tI % 64; ny = tI / 64;
  }
  const int k0 = kx << 6, n0 = ny << 6;
  {
    const int r = tid >> 4, c4 = tid & 15;
#pragma unroll
    for (int p = 0; p < 4; ++p) {
      int kr = r + (p << 4);
      float4 v = *(const float4*)(W + (size_t)(k0 + kr) * N + n0 + (c4 << 2));
      tile[kr][(c4 << 2) + 0] = v.x;
      tile[kr][(c4 << 2) + 1] = v.y;
      tile[kr][(c4 << 2) + 2] = v.z;
      tile[kr][(c4 << 2) + 3] = v.w;
    }
  }
  __syncthreads();
  {
    const int n = tid >> 2, kq = tid & 3;
    bf16x8 o0, o1;
#pragma unroll
    for (int e = 0; e < 8; ++e) o0[e] = (short)f2bf(tile[(kq << 4) + e][n]);
#pragma unroll
    for (int e = 0; e < 8; ++e) o1[e] = (short)f2bf(tile[(kq << 4) + 8 + e][n]);
    unsigned short* dst = Wt + (size_t)(n0 + n) * K + k0 + (kq << 4);
    *(bf16x8*)dst = o0;
    *(bf16x8*)(dst + 8) = o1;
  }
}

// ---------------- fused reduce(bf16 partials) + layernorm ----------------
__global__ __launch_bounds__(256) void redln_k(float* __restrict__ x,
    const unsigned short* __restrict__ P, const float* __restrict__ bias,
    const float* __restrict__ lw, const float* __restrict__ lb,
    unsigned short* __restrict__ out, int splits)
{
  int row = blockIdx.x * 4 + (threadIdx.x >> 6);
  int lane = threadIdx.x & 63;
  const int c0 = lane * 16;
  float* xw = x + (size_t)row * CC + c0;
  float4 v[4];
#pragma unroll
  for (int i = 0; i < 4; ++i) v[i] = *(const float4*)(xw + i * 4);
  {
    const float4* b4 = (const float4*)(bias + c0);
#pragma unroll
    for (int i = 0; i < 4; ++i) {
      float4 bv = b4[i];
      v[i].x += bv.x; v[i].y += bv.y; v[i].z += bv.z; v[i].w += bv.w;
    }
  }
  for (int sp = 0; sp < splits; ++sp) {
    const unsigned short* pp = P + ((size_t)sp * 2048 + row) * CC + c0;
    bf16x8 pa = *(const bf16x8*)pp;
    bf16x8 pb = *(const bf16x8*)(pp + 8);
    v[0].x += bf2f((unsigned short)pa[0]); v[0].y += bf2f((unsigned short)pa[1]);
    v[0].z += bf2f((unsigned short)pa[2]); v[0].w += bf2f((unsigned short)pa[3]);
    v[1].x += bf2f((unsigned short)pa[4]); v[1].y += bf2f((unsigned short)pa[5]);
    v[1].z += bf2f((unsigned short)pa[6]); v[1].w += bf2f((unsigned short)pa[7]);
    v[2].x += bf2f((unsigned short)pb[0]); v[2].y += bf2f((unsigned short)pb[1]);
    v[2].z += bf2f((unsigned short)pb[2]); v[2].w += bf2f((unsigned short)pb[3]);
    v[3].x += bf2f((unsigned short)pb[4]); v[3].y += bf2f((unsigned short)pb[5]);
    v[3].z += bf2f((unsigned short)pb[6]); v[3].w += bf2f((unsigned short)pb[7]);
  }
  float s = 0.f, ss = 0.f;
#pragma unroll
  for (int i = 0; i < 4; ++i) {
    *(float4*)(xw + i * 4) = v[i];
    s  += v[i].x + v[i].y + v[i].z + v[i].w;
    ss += v[i].x*v[i].x + v[i].y*v[i].y + v[i].z*v[i].z + v[i].w*v[i].w;
  }
#pragma unroll
  for (int off = 1; off < 64; off <<= 1) {
    s  += __shfl_xor(s, off, 64);
    ss += __shfl_xor(ss, off, 64);
  }
  float mu = s * (1.f / CC);
  float var = ss * (1.f / CC) - mu * mu;
  float rstd = rsqrtf(var + 1e-5f);
  const float* wr = lw + c0;
  const float* br = lb + c0;
  unsigned q[8];
#pragma unroll
  for (int i = 0; i < 4; ++i) {
    float4 wv = *(const float4*)(wr + i * 4);
    float4 bv = *(const float4*)(br + i * 4);
    float o0 = (v[i].x - mu) * rstd * wv.x + bv.x;
    float o1 = (v[i].y - mu) * rstd * wv.y + bv.y;
    float o2 = (v[i].z - mu) * rstd * wv.z + bv.z;
    float o3 = (v[i].w - mu) * rstd * wv.w + bv.w;
    q[i*2+0] = pk2(o0, o1);
    q[i*2+1] = pk2(o2, o3);
  }
  uint4* op = (uint4*)(out + (size_t)row * CC + c0);
  op[0] = make_uint4(q[0], q[1], q[2], q[3]);
  op[1] = make_uint4(q[4], q[5], q[6], q[7]);
}

// ---------------- GEMM modes ----------------
#define MODE_QKV  0
#define MODE_PART 1
#define MODE_FC   2

// Round-14 GEMM (measured best): 128x128 tile, single 32KB LDS buffer,
// 2 barriers/K-step, 32x32x16 MFMA, chunk swizzle (kq ^= row&7, both sides).
template<int MODE>
__global__ __launch_bounds__(256, 4) void gemm_k(
    const unsigned short* __restrict__ A,
    const unsigned short* __restrict__ Wt,
    const float* __restrict__ bias,
    unsigned short* __restrict__ obf,
    unsigned short* __restrict__ q_o,
    unsigned short* __restrict__ k_o,
    unsigned short* __restrict__ v_o,
    int M, int N, int K, int kchunk, int ncol0)
{
  __shared__ alignas(16) unsigned short Asm[128 * 64];
  __shared__ alignas(16) unsigned short Bsm[128 * 64];
  const int tid  = threadIdx.x;
  const int wave = tid >> 6, lane = tid & 63;
  const int rl = lane & 31, hi = lane >> 5;
  const int nTM = M >> 7, nTN = N >> 7;
  int bid = blockIdx.x;
  const int mt = bid % nTM; bid /= nTM;
  const int nt = bid % nTN;
  const int s  = bid / nTN;
  const int m0 = mt << 7, n0 = nt << 7;
  const int kb = s * kchunk;
  const int nIter = kchunk >> 6;
  const int wm = (wave >> 1) << 6, wn = (wave & 1) << 6;
  f32x16 acc[2][2] = {};

#define STAGE(K0)                                                             \
  {                                                                           \
    _Pragma("unroll")                                                         \
    for (int c = 0; c < 4; ++c) {                                             \
      const int seg = (wave << 2) + c;                                        \
      const int g = (seg << 6) + lane;                                        \
      const int row = g >> 3, kq = g & 7;                                     \
      const int kqs = kq ^ (row & 7);                                         \
      const unsigned short* asrc = A  + (size_t)(m0 + row) * K + (K0) + (kqs << 3); \
      const unsigned short* bsrc = Wt + (size_t)(n0 + row) * K + (K0) + (kqs << 3); \
      __builtin_amdgcn_global_load_lds(GPTR(asrc), LPTR(&Asm[seg << 9]), 16, 0, 0); \
      __builtin_amdgcn_global_load_lds(GPTR(bsrc), LPTR(&Bsm[seg << 9]), 16, 0, 0); \
    }                                                                         \
  }

  for (int t = 0; t < nIter; ++t) {
    STAGE(kb + (t << 6));
    __syncthreads();                     // vmcnt(0) drain + barrier
#pragma unroll
    for (int sl = 0; sl < 4; ++sl) {
      const int c = sl * 2 + hi;                 // 16B chunk index within row
      const int cs = (c ^ (rl & 7)) << 3;        // swizzled element offset
      bf16x8 a0 = *(const bf16x8*)(Asm + ((wm + rl) << 6) + cs);
      bf16x8 a1 = *(const bf16x8*)(Asm + ((wm + 32 + rl) << 6) + cs);
      bf16x8 b0 = *(const bf16x8*)(Bsm + ((wn + rl) << 6) + cs);
      bf16x8 b1 = *(const bf16x8*)(Bsm + ((wn + 32 + rl) << 6) + cs);
      acc[0][0] = mfma32_bf16(a0, b0, acc[0][0]);
      acc[0][1] = mfma32_bf16(a0, b1, acc[0][1]);
      acc[1][0] = mfma32_bf16(a1, b0, acc[1][0]);
      acc[1][1] = mfma32_bf16(a1, b1, acc[1][1]);
    }
    __syncthreads();                     // all waves done reading before restage
  }
#undef STAGE

  // C/D layout (m74/m101): col = lane&31, row = (reg&3) + 8*(reg>>2) + 4*(lane>>5)
#pragma unroll
  for (int j = 0; j < 2; ++j) {
    int gc = n0 + wn + j * 32 + rl;
    int gcol = ncol0 + gc;
    float bv = (MODE == MODE_PART) ? 0.f : bias[gcol];
#pragma unroll
    for (int i = 0; i < 2; ++i) {
      int gr0 = m0 + wm + i * 32 + 4 * hi;
#pragma unroll
      for (int reg = 0; reg < 16; ++reg) {
        int grow = gr0 + (reg & 3) + 8 * (reg >> 2);
        float val = acc[i][j][reg] + bv;
        if (MODE == MODE_QKV) {
          int which = gcol >> 10;
          int head = (gcol >> 6) & 15;
          int d = gcol & 63;
          int bb = grow >> 10, tt2 = grow & (TT - 1);
          size_t bhb = ((size_t)((bb << 4) + head)) << 16;
          if (which == 2)      v_o[bhb + ((size_t)d << 10) + tt2] = f2bf(val);
          else if (which == 1) k_o[bhb + ((size_t)tt2 << 6) + d] = f2bf(val);
          else                 q_o[bhb + ((size_t)tt2 << 6) + d] = f2bf(val);
        } else if (MODE == MODE_FC) {
          val = (val >= 0.f) ? val : 0.01f * val;
          obf[(size_t)grow * N + gc] = f2bf(val);
        } else {  // MODE_PART: bf16 partials
          obf[((size_t)s * M + grow) * N + gc] = f2bf(val);
        }
      }
    }
  }
}

// ---------------- flash attention (causal), layers 0-2 ----------------
// 128-key tiles; T13 defer-rescale; V^T input.
__global__ __launch_bounds__(256) void attn_k(
    const unsigned short* __restrict__ Qb,
    const unsigned short* __restrict__ Kb,
    const unsigned short* __restrict__ Vb,   // [bh][d][t]
    unsigned short* __restrict__ ybuf)
{
  __shared__ alignas(16) unsigned short Ksm[128][72];
  __shared__ alignas(16) unsigned short Vtsm[64][128];
  __shared__ alignas(16) unsigned short Psm[4][16][136];
  const int tid = threadIdx.x;
  const int wave = tid >> 6, lane = tid & 63;
  const int lg = lane >> 4, ll = lane & 15;
  const int qt = blockIdx.x & 15, bh = blockIdx.x >> 4;
  const int b = bh >> 4, h = bh & 15;
  const size_t base = (size_t)bh << 16;
  const int q0 = qt << 6;
  const float SC = 0.125f * 1.44269504f;

  const int qrow = q0 + wave * 16 + ll;
  bf16x8 aq0 = *(const bf16x8*)(Qb + base + ((size_t)qrow << 6) + (lg << 3));
  bf16x8 aq1 = *(const bf16x8*)(Qb + base + ((size_t)qrow << 6) + 32 + (lg << 3));

  f32x4 accy[4] = {};
  float m_run[4], l_run[4];
#pragma unroll
  for (int r = 0; r < 4; ++r) { m_run[r] = -1e30f; l_run[r] = 0.f; }

  const int sk_row = tid >> 3, sk_cq = tid & 7;
  const int sv_d = tid & 63, sv_kq0 = tid >> 6;
  const int qg0 = q0 + wave * 16 + (lg << 2);

  for (int kbase = 0; kbase < q0 + 64; kbase += 128) {
#pragma unroll
    for (int p = 0; p < 4; ++p) {
      int r = sk_row + (p << 5);
      bf16x8 kv = *(const bf16x8*)(Kb + base + ((size_t)(kbase + r) << 6) + (sk_cq << 3));
      *(bf16x8*)&Ksm[r][sk_cq << 3] = kv;
    }
#pragma unroll
    for (int p = 0; p < 4; ++p) {
      int kq8 = sv_kq0 + (p << 2);
      bf16x8 wv = *(const bf16x8*)(Vb + base + ((size_t)sv_d << 10) + kbase + (kq8 << 3));
      int u = kq8 ^ (sv_d & 7);
      *(bf16x8*)&Vtsm[sv_d][u << 3] = wv;
    }
    __syncthreads();

    int kkmax = ((q0 + 63 - kbase) >> 4) + 1;
    if (kkmax > 8) kkmax = 8;
    const int kkmax2 = (kkmax + 1) & ~1;
    const int jmax = kkmax2 >> 1;

    float p_[8][4];
    float rmax[4] = {-1e30f, -1e30f, -1e30f, -1e30f};
    __builtin_amdgcn_s_setprio(1);
#pragma unroll
    for (int kk = 0; kk < 8; ++kk) {
      if (kk < kkmax) {
        f32x4 z = {};
        bf16x8 bk0 = *(const bf16x8*)&Ksm[kk * 16 + ll][lg << 3];
        bf16x8 bk1 = *(const bf16x8*)&Ksm[kk * 16 + ll][32 + (lg << 3)];
        z = mfma_bf16(aq0, bk0, z);
        z = mfma_bf16(aq1, bk1, z);
        int key = kbase + kk * 16 + ll;
#pragma unroll
        for (int r = 0; r < 4; ++r) {
          float v = z[r] * SC;
          v = (key > qg0 + r) ? -1e30f : v;
          p_[kk][r] = v;
          rmax[r] = fmaxf(rmax[r], v);
        }
      } else {
#pragma unroll
        for (int r = 0; r < 4; ++r) p_[kk][r] = -1e30f;
      }
    }
    __builtin_amdgcn_s_setprio(0);
#pragma unroll
    for (int off = 1; off < 16; off <<= 1)
#pragma unroll
      for (int r = 0; r < 4; ++r)
        rmax[r] = fmaxf(rmax[r], __shfl_xor(rmax[r], off, 64));

    int ok = (rmax[0] <= m_run[0] + 8.f) & (rmax[1] <= m_run[1] + 8.f) &
             (rmax[2] <= m_run[2] + 8.f) & (rmax[3] <= m_run[3] + 8.f);
    const int skip = __all(ok);
    float alpha[4];
    if (!skip) {
#pragma unroll
      for (int r = 0; r < 4; ++r) {
        float mn = fmaxf(m_run[r], rmax[r]);
        alpha[r] = exp2f(m_run[r] - mn);
        m_run[r] = mn;
      }
    }
    float rsum[4] = {0.f, 0.f, 0.f, 0.f};
#pragma unroll
    for (int kk = 0; kk < 8; ++kk)
#pragma unroll
      for (int r = 0; r < 4; ++r) {
        float e = exp2f(p_[kk][r] - m_run[r]);
        p_[kk][r] = e;
        rsum[r] += e;
      }
#pragma unroll
    for (int off = 1; off < 16; off <<= 1)
#pragma unroll
      for (int r = 0; r < 4; ++r)
        rsum[r] += __shfl_xor(rsum[r], off, 64);
    if (!skip) {
#pragma unroll
      for (int r = 0; r < 4; ++r)
        l_run[r] = l_run[r] * alpha[r] + rsum[r];
#pragma unroll
      for (int df = 0; df < 4; ++df)
#pragma unroll
        for (int r = 0; r < 4; ++r)
          accy[df][r] *= alpha[r];
    } else {
#pragma unroll
      for (int r = 0; r < 4; ++r)
        l_run[r] += rsum[r];
    }

#pragma unroll
    for (int kk = 0; kk < 8; ++kk)
      if (kk < kkmax2)
#pragma unroll
        for (int r = 0; r < 4; ++r)
          Psm[wave][(lg << 2) + r][kk * 16 + ll] = f2bf(p_[kk][r]);

    __builtin_amdgcn_s_setprio(1);
#pragma unroll
    for (int j = 0; j < 4; ++j) {
      if (j < jmax) {
        bf16x8 pa = *(const bf16x8*)&Psm[wave][ll][j * 32 + (lg << 3)];
#pragma unroll
        for (int df = 0; df < 4; ++df) {
          int d = df * 16 + ll;
          int u = ((j << 2) + lg) ^ (d & 7);
          bf16x8 bv = *(const bf16x8*)&Vtsm[d][u << 3];
          accy[df] = mfma_bf16(pa, bv, accy[df]);
        }
      }
    }
    __builtin_amdgcn_s_setprio(0);
    __syncthreads();
  }

#pragma unroll
  for (int df = 0; df < 4; ++df)
#pragma unroll
    for (int r = 0; r < 4; ++r) {
      int qr = qg0 + r;
      float y = accy[df][r] / l_run[r];
      ybuf[(((size_t)((b << 10) + qr)) << 10) + (h << 6) + df * 16 + ll] = f2bf(y);
    }
}

// ---------------- layer-3 tail (last position only; all k-slab parallel) ----------------

__global__ __launch_bounds__(256) void qlast_k(
    const unsigned short* __restrict__ hbuf,
    const float* __restrict__ Wq,
    float* __restrict__ qpart)
{
  __shared__ float xs[2][128];
  const int tid = threadIdx.x, ks = blockIdx.y;
  {
    const int b = tid >> 7, j = tid & 127;
    xs[b][j] = bf2f(hbuf[((size_t)(b * TT + TT - 1)) * CC + ks * 128 + j]);
  }
  __syncthreads();
  const int n = blockIdx.x * 256 + tid;
  float a0 = 0.f, a1 = 0.f;
  const float* wp = Wq + (size_t)(ks * 128) * 3072 + n;
  for (int k = 0; k < 128; k += 8)
#pragma unroll
    for (int u = 0; u < 8; ++u) {
      float w = wp[(size_t)(k + u) * 3072];
      a0 += xs[0][k + u] * w;
      a1 += xs[1][k + u] * w;
    }
  qpart[(size_t)(ks * 2 + 0) * 1024 + n] = a0;
  qpart[(size_t)(ks * 2 + 1) * 1024 + n] = a1;
}

__global__ __launch_bounds__(256) void attnlast2_k(
    const float* __restrict__ qpart, const float* __restrict__ bq,
    const unsigned short* __restrict__ Kb,
    const unsigned short* __restrict__ Vb,   // [bh][d][t]
    float* __restrict__ y_last)
{
  __shared__ float qs[64];
  __shared__ float wm[4], wl[4], wacc[4][64];
  const int tid = threadIdx.x;
  const int wave = tid >> 6, lane = tid & 63;
  const int bh = blockIdx.x;
  const int b = bh >> 4, h = bh & 15;
  const size_t base = (size_t)bh << 16;
  if (tid < 64) {
    const int col = h * 64 + tid;
    float q = bq[col];
#pragma unroll
    for (int ks = 0; ks < 8; ++ks)
      q += qpart[(size_t)(ks * 2 + b) * 1024 + col];
    qs[tid] = q;
  }
  __syncthreads();

  float m_w = -1e30f, l_w = 0.f, acc = 0.f;
  for (int ks = 0; ks < 4; ++ks) {
    const int key = ks * 256 + wave * 64 + lane;
    float s = 0.f;
    const unsigned short* kp = Kb + base + ((size_t)key << 6);
#pragma unroll
    for (int o = 0; o < 8; ++o) {
      bf16x8 kv = *(const bf16x8*)(kp + (o << 3));
#pragma unroll
      for (int e = 0; e < 8; ++e)
        s += qs[(o << 3) + e] * bf2f((unsigned short)kv[e]);
    }
    s *= 0.125f;
    float m = s;
#pragma unroll
    for (int off = 1; off < 64; off <<= 1)
      m = fmaxf(m, __shfl_xor(m, off, 64));
    float mn = fmaxf(m_w, m);
    float alpha = __expf(m_w - mn);
    m_w = mn;
    float p = __expf(s - mn);
    float ps = p;
#pragma unroll
    for (int off = 1; off < 64; off <<= 1)
      ps += __shfl_xor(ps, off, 64);
    l_w = l_w * alpha + ps;
    float a2 = 0.f;
    const unsigned short* vp = Vb + base + ((size_t)lane << 10) + ks * 256 + wave * 64;
#pragma unroll
    for (int j8 = 0; j8 < 8; ++j8) {
      bf16x8 vv = *(const bf16x8*)(vp + (j8 << 3));
#pragma unroll
      for (int e = 0; e < 8; ++e) {
        float pj = __shfl(p, (j8 << 3) + e, 64);
        a2 += pj * bf2f((unsigned short)vv[e]);
      }
    }
    acc = acc * alpha + a2;
  }
  if (lane == 0) { wm[wave] = m_w; wl[wave] = l_w; }
  wacc[wave][lane] = acc;
  __syncthreads();
  if (wave == 0) {
    float m0 = fmaxf(fmaxf(wm[0], wm[1]), fmaxf(wm[2], wm[3]));
    float lt = 0.f, at = 0.f;
#pragma unroll
    for (int sI = 0; sI < 4; ++sI) {
      float f = __expf(wm[sI] - m0);
      lt += wl[sI] * f;
      at += wacc[sI][lane] * f;
    }
    y_last[b * CC + h * 64 + lane] = at / lt;
  }
}

__global__ __launch_bounds__(256) void projpart_k(
    const float* __restrict__ ylast,
    const float* __restrict__ W,
    float* __restrict__ ppart)
{
  __shared__ float xs[2][128];
  const int tid = threadIdx.x, ks = blockIdx.y;
  {
    const int b = tid >> 7, j = tid & 127;
    xs[b][j] = ylast[b * 1024 + ks * 128 + j];
  }
  __syncthreads();
  const int n = blockIdx.x * 256 + tid;
  float a0 = 0.f, a1 = 0.f;
  const float* wp = W + (size_t)(ks * 128) * 1024 + n;
  for (int k = 0; k < 128; k += 8)
#pragma unroll
    for (int u = 0; u < 8; ++u) {
      float w = wp[(size_t)(k + u) * 1024];
      a0 += xs[0][k + u] * w;
      a1 += xs[1][k + u] * w;
    }
  ppart[(size_t)(ks * 2 + 0) * 1024 + n] = a0;
  ppart[(size_t)(ks * 2 + 1) * 1024 + n] = a1;
}

__global__ __launch_bounds__(256) void fclast_k(
    const float* __restrict__ x, const float* __restrict__ ppart,
    const float* __restrict__ pbias,
    const float* __restrict__ lw, const float* __restrict__ lb,
    const float* __restrict__ W,
    float* __restrict__ fcpart)
{
  __shared__ float xs[2][1024];
  const int tid = threadIdx.x;
  const int wave = tid >> 6, lane = tid & 63;
  if (wave < 2) {
    const int c0 = lane * 16;
    const float* xr = x + ((size_t)(wave * TT + TT - 1)) * CC + c0;
    float4 v[4];
    float s = 0.f, ss = 0.f;
#pragma unroll
    for (int i = 0; i < 4; ++i) {
      v[i] = *(const float4*)(xr + i * 4);
      float4 bv = *(const float4*)(pbias + c0 + i * 4);
      v[i].x += bv.x; v[i].y += bv.y; v[i].z += bv.z; v[i].w += bv.w;
    }
#pragma unroll
    for (int sp = 0; sp < 8; ++sp) {
      const float* pp = ppart + (size_t)(sp * 2 + wave) * 1024 + c0;
#pragma unroll
      for (int i = 0; i < 4; ++i) {
        float4 pv = *(const float4*)(pp + i * 4);
        v[i].x += pv.x; v[i].y += pv.y; v[i].z += pv.z; v[i].w += pv.w;
      }
    }
#pragma unroll
    for (int i = 0; i < 4; ++i) {
      s  += v[i].x + v[i].y + v[i].z + v[i].w;
      ss += v[i].x*v[i].x + v[i].y*v[i].y + v[i].z*v[i].z + v[i].w*v[i].w;
    }
#pragma unroll
    for (int off = 1; off < 64; off <<= 1) {
      s  += __shfl_xor(s, off, 64);
      ss += __shfl_xor(ss, off, 64);
    }
    float mu = s * (1.f / CC);
    float var = ss * (1.f / CC) - mu * mu;
    float rstd = rsqrtf(var + 1e-5f);
#pragma unroll
    for (int i = 0; i < 4; ++i) {
      float4 wv = *(const float4*)(lw + c0 + i * 4);
      float4 bv = *(const float4*)(lb + c0 + i * 4);
      xs[wave][c0 + i * 4 + 0] = (v[i].x - mu) * rstd * wv.x + bv.x;
      xs[wave][c0 + i * 4 + 1] = (v[i].y - mu) * rstd * wv.y + bv.y;
      xs[wave][c0 + i * 4 + 2] = (v[i].z - mu) * rstd * wv.z + bv.z;
      xs[wave][c0 + i * 4 + 3] = (v[i].w - mu) * rstd * wv.w + bv.w;
    }
  }
  __syncthreads();
  const int ks = blockIdx.y;
  const int n = blockIdx.x * 256 + tid;
  float a0 = 0.f, a1 = 0.f;
  const float* wp = W + (size_t)(ks * 128) * 4096 + n;
  for (int k = 0; k < 128; k += 8)
#pragma unroll
    for (int u = 0; u < 8; ++u) {
      float w = wp[(size_t)(k + u) * 4096];
      a0 += xs[0][ks * 128 + k + u] * w;
      a1 += xs[1][ks * 128 + k + u] * w;
    }
  fcpart[(size_t)(ks * 2 + 0) * 4096 + n] = a0;
  fcpart[(size_t)(ks * 2 + 1) * 4096 + n] = a1;
}

__global__ __launch_bounds__(256) void fcprojpart_k(
    const float* __restrict__ fcpart, const float* __restrict__ fcbias,
    const float* __restrict__ W,
    float* __restrict__ fppart)
{
  __shared__ float hs[2][512];
  const int tid = threadIdx.x, ks = blockIdx.y;
#pragma unroll
  for (int i = 0; i < 4; ++i) {
    const int e = tid + 256 * i;
    const int b = e >> 9, j = e & 511;
    const int c = ks * 512 + j;
    float v = fcbias[c];
#pragma unroll
    for (int sp = 0; sp < 8; ++sp)
      v += fcpart[(size_t)(sp * 2 + b) * 4096 + c];
    hs[b][j] = (v >= 0.f) ? v : 0.01f * v;
  }
  __syncthreads();
  const int n = blockIdx.x * 256 + tid;
  float a0 = 0.f, a1 = 0.f;
  const float* wp = W + (size_t)(ks * 512) * 1024 + n;
  for (int k = 0; k < 512; k += 8)
#pragma unroll
    for (int u = 0; u < 8; ++u) {
      float w = wp[(size_t)(k + u) * 1024];
      a0 += hs[0][k + u] * w;
      a1 += hs[1][k + u] * w;
    }
  fppart[(size_t)(ks * 2 + 0) * 1024 + n] = a0;
  fppart[(size_t)(ks * 2 + 1) * 1024 + n] = a1;
}

__global__ __launch_bounds__(256) void lnfmerge_k(const float* __restrict__ x,
    const float* __restrict__ ppart, const float* __restrict__ pbias,
    const float* __restrict__ fppart, const float* __restrict__ fpbias,
    const float* __restrict__ lw, const float* __restrict__ lb,
    float* __restrict__ xf)
{
  __shared__ float rs[4], rss[4];
  const int row = blockIdx.x;
  const int tid = threadIdx.x;
  const int wave = tid >> 6, lane = tid & 63;
  const int c0 = tid * 4;
  float4 v = *(const float4*)(x + ((size_t)(row * TT + TT - 1)) * CC + c0);
  {
    float4 b1 = *(const float4*)(pbias + c0);
    float4 b2 = *(const float4*)(fpbias + c0);
    v.x += b1.x + b2.x; v.y += b1.y + b2.y;
    v.z += b1.z + b2.z; v.w += b1.w + b2.w;
  }
#pragma unroll
  for (int sp = 0; sp < 8; ++sp) {
    float4 a = *(const float4*)(ppart + (size_t)(sp * 2 + row) * 1024 + c0);
    float4 b = *(const float4*)(fppart + (size_t)(sp * 2 + row) * 1024 + c0);
    v.x += a.x + b.x; v.y += a.y + b.y;
    v.z += a.z + b.z; v.w += a.w + b.w;
  }
  float s  = v.x + v.y + v.z + v.w;
  float ss = v.x*v.x + v.y*v.y + v.z*v.z + v.w*v.w;
#pragma unroll
  for (int off = 1; off < 64; off <<= 1) {
    s  += __shfl_xor(s, off, 64);
    ss += __shfl_xor(ss, off, 64);
  }
  if (lane == 0) { rs[wave] = s; rss[wave] = ss; }
  __syncthreads();
  s  = rs[0] + rs[1] + rs[2] + rs[3];
  ss = rss[0] + rss[1] + rss[2] + rss[3];
  float mu = s * (1.f / CC);
  float var = ss * (1.f / CC) - mu * mu;
  float rstd = rsqrtf(var + 1e-5f);
  float4 wv = *(const float4*)(lw + c0);
  float4 bv = *(const float4*)(lb + c0);
  float4 o;
  o.x = (v.x - mu) * rstd * wv.x + bv.x;
  o.y = (v.y - mu) * rstd * wv.y + bv.y;
  o.z = (v.z - mu) * rstd * wv.z + bv.z;
  o.w = (v.w - mu) * rstd * wv.w + bv.w;
  *(float4*)(xf + (size_t)row * CC + c0) = o;
}

// ---------------- lm_head ----------------
__global__ __launch_bounds__(256) void head_k(const float* __restrict__ xf,
    const float* __restrict__ wte, float* __restrict__ out)
{
  int v = (blockIdx.x << 2) + (threadIdx.x >> 6);
  if (v >= VOCAB) return;
  int lane = threadIdx.x & 63;
  const float4* wr = (const float4*)(wte + (size_t)v * CC);
  const float4* x0 = (const float4*)xf;
  const float4* x1 = (const float4*)(xf + CC);
  float a0 = 0.f, a1 = 0.f;
#pragma unroll
  for (int i = 0; i < 4; ++i) {
    float4 wv = wr[lane + i * 64];
    float4 p0 = x0[lane + i * 64];
    float4 p1 = x1[lane + i * 64];
    a0 += wv.x * p0.x + wv.y * p0.y + wv.z * p0.z + wv.w * p0.w;
    a1 += wv.x * p1.x + wv.y * p1.y + wv.z * p1.z + wv.w * p1.w;
  }
#pragma unroll
  for (int off = 1; off < 64; off <<= 1) {
    a0 += __shfl_xor(a0, off, 64);
    a1 += __shfl_xor(a1, off, 64);
  }
  if (lane == 0) {
    out[v] = a0;
    out[VOCAB + v] = a1;
  }
}

// ---------------- host orchestration ----------------
extern "C" void kernel_launch(void* const* d_in, const int* in_sizes, int n_in,
                              void* d_out, int out_size, void* d_ws, size_t ws_size,
                              hipStream_t stream)
{
  const int*   idx      = (const int*)d_in[0];
  const float* wte      = (const float*)d_in[1];
  const float* wpe      = (const float*)d_in[2];
  const float* ln1_w    = (const float*)d_in[3];
  const float* ln1_b    = (const float*)d_in[4];
  const float* attn_w   = (const float*)d_in[5];
  const float* attn_b   = (const float*)d_in[6];
  const float* proj_w   = (const float*)d_in[7];
  const float* proj_b   = (const float*)d_in[8];
  const float* ln2_w    = (const float*)d_in[9];
  const float* ln2_b    = (const float*)d_in[10];
  const float* fc_w     = (const float*)d_in[11];
  const float* fc_b     = (const float*)d_in[12];
  const float* fcproj_w = (const float*)d_in[13];
  const float* fcproj_b = (const float*)d_in[14];
  const float* lnf_w    = (const float*)d_in[15];
  const float* lnf_b    = (const float*)d_in[16];
  float* out = (float*)d_out;

  const size_t MB = 1u << 20;
  char* ws = (char*)d_ws;
  float*          x   = (float*)ws;                       // 8 MiB
  unsigned short* h   = (unsigned short*)(ws + 8*MB);     // 4 MiB
  unsigned short* qb  = (unsigned short*)(ws + 12*MB);    // 4 MiB
  unsigned short* kb_ = (unsigned short*)(ws + 16*MB);    // 4 MiB
  unsigned short* vb  = (unsigned short*)(ws + 20*MB);    // 4 MiB (V^T)
  unsigned short* yb  = (unsigned short*)(ws + 24*MB);    // 4 MiB
  unsigned short* hf  = (unsigned short*)(ws + 28*MB);    // 16 MiB
  char* sm = ws + 44*MB;
  float* xf     = (float*)(sm + 0);
  float* ylast  = (float*)(sm + 16*1024);
  float* qpart  = (float*)(sm + 64*1024);
  float* ppart  = (float*)(sm + 128*1024);
  float* fppart = (float*)(sm + 192*1024);
  float* fcpart = (float*)(sm + 256*1024);
  unsigned short* wt_attn   = (unsigned short*)(ws + 46*MB);
  unsigned short* wt_proj   = (unsigned short*)(ws + 70*MB);
  unsigned short* wt_fc     = (unsigned short*)(ws + 76*MB);
  unsigned short* wt_fcproj = (unsigned short*)(ws + 100*MB);
  unsigned short* Ppart     = (unsigned short*)(ws + 124*MB);

  prep_k<<<2048 + 9984, 256, 0, stream>>>(idx, wte, wpe, ln1_w, ln1_b, x, h,
      attn_w, wt_attn, proj_w, wt_proj, fc_w, wt_fc, fcproj_w, wt_fcproj);

  for (int l = 0; l < 3; ++l) {
    gemm_k<MODE_QKV><<<16 * 24, 256, 0, stream>>>(h,
        wt_attn + (size_t)l * 3072 * 1024, attn_b + (size_t)l * 3 * CC,
        nullptr, qb, kb_, vb, 2048, 3072, 1024, 1024, 0);
    attn_k<<<NBATCH * NHEAD * 16, 256, 0, stream>>>(qb, kb_, vb, yb);
    // proj: split-K 2 (halved partial traffic vs split-4)
    gemm_k<MODE_PART><<<16 * 8 * 2, 256, 0, stream>>>(yb,
        wt_proj + (size_t)l * 1024 * 1024, nullptr,
        Ppart, nullptr, nullptr, nullptr, 2048, 1024, 1024, 512, 0);
    redln_k<<<512, 256, 0, stream>>>(x, Ppart, proj_b + l * CC,
        ln2_w + l * CC, ln2_b + l * CC, h, 2);
    gemm_k<MODE_FC><<<16 * 32, 256, 0, stream>>>(h,
        wt_fc + (size_t)l * 1024 * 4096, fc_b + (size_t)l * 4 * CC,
        hf, nullptr, nullptr, nullptr, 2048, 4096, 1024, 1024, 0);
    gemm_k<MODE_PART><<<16 * 8 * 4, 256, 0, stream>>>(hf,
        wt_fcproj + (size_t)l * 4096 * 1024, nullptr,
        Ppart, nullptr, nullptr, nullptr, 2048, 1024, 4096, 1024, 0);
    redln_k<<<512, 256, 0, stream>>>(x, Ppart, fcproj_b + l * CC,
        ln1_w + (l + 1) * CC, ln1_b + (l + 1) * CC, h, 4);
  }

  // ---- layer 3: K/V for all positions, everything else last-position only ----
  {
    const int l = 3;
    gemm_k<MODE_QKV><<<16 * 16, 256, 0, stream>>>(h,
        wt_attn + (size_t)l * 3072 * 1024 + (size_t)1024 * 1024,
        attn_b + (size_t)l * 3 * CC,
        nullptr, qb, kb_, vb, 2048, 2048, 1024, 1024, 1024);
    qlast_k<<<dim3(4, 8), 256, 0, stream>>>(h,
        attn_w + (size_t)l * CC * 3 * CC, qpart);
    attnlast2_k<<<32, 256, 0, stream>>>(qpart, attn_b + (size_t)l * 3 * CC,
        kb_, vb, ylast);
    projpart_k<<<dim3(4, 8), 256, 0, stream>>>(ylast,
        proj_w + (size_t)l * CC * CC, ppart);
    fclast_k<<<dim3(16, 8), 256, 0, stream>>>(x, ppart, proj_b + l * CC,
        ln2_w + l * CC, ln2_b + l * CC,
        fc_w + (size_t)l * CC * 4 * CC, fcpart);
    fcprojpart_k<<<dim3(4, 8), 256, 0, stream>>>(fcpart,
        fc_b + (size_t)l * 4 * CC, fcproj_w + (size_t)l * 4 * CC * CC, fppart);
    lnfmerge_k<<<2, 256, 0, stream>>>(x, ppart, proj_b + l * CC,
        fppart, fcproj_b + l * CC, lnf_w, lnf_b, xf);
  }

  head_k<<<(VOCAB + 3) / 4, 256, 0, stream>>>(xf, wte, out);
}